// Round 3
// baseline (118.630 us; speedup 1.0000x reference)
//
#include <hip/hip_runtime.h>

// Problem constants
#define B_   16
#define C_   256
#define N_   4096   // H*W
#define NH_  8
#define D_   512    // N_/NH_
#define BH_  128    // B_*NH_

typedef __bf16  bf16x8  __attribute__((ext_vector_type(8)));
typedef __bf16  bf16x4  __attribute__((ext_vector_type(4)));
typedef float   floatx4 __attribute__((ext_vector_type(4)));

// XOR swizzle of 8-element column blocks within a 64-wide bf16 LDS row
__device__ __forceinline__ int sw(int row, int kb) { return kb ^ (row & 7); }

// async global->LDS, 16B per lane. LDS dest is wave-uniform base + lane*16.
__device__ __forceinline__ void gl_lds16(const void* g, void* l) {
    __builtin_amdgcn_global_load_lds(
        (const __attribute__((address_space(1))) unsigned int*)g,
        (__attribute__((address_space(3))) unsigned int*)l, 16, 0, 0);
}

// ---------------------------------------------------------------------------
// gamma==0 fast path (algebraic zero-skip, exact):
//   y = gamma*out + x, out = attn @ X is a convex combination of x's values
//   (softmax rows sum to 1) -> finite whenever x is finite. Hence gamma == 0
//   => y == x bit-exactly, independent of the attention path. The copy is done
//   in k_prep (first kernel) so no dead launches precede it; k_attn exits on a
//   uniform scalar branch. Full MFMA pipeline is live for gamma != 0.
// ---------------------------------------------------------------------------

// ---------------------------------------------------------------------------
// Kernel 0: gamma!=0: x (fp32 [b][c][n]) -> Xbf (bf16) + Xt (bf16 [bh][d][c]).
//           gamma==0: y = x straight copy at HBM bandwidth.
// grid 1024, block 256; live path processes 4 64x64 tiles per block.
// ---------------------------------------------------------------------------
__global__ __launch_bounds__(256) void k_prep(const float* __restrict__ x,
                                              __bf16* __restrict__ xbf,
                                              __bf16* __restrict__ xt,
                                              const float* __restrict__ gamma,
                                              float* __restrict__ y) {
    const float g = *gamma;
    if (g == 0.0f) {
        // y = x exactly: 16.7M floats = 4.19M float4; 262144 threads x 16 each.
        const float4* xi = (const float4*)x;
        float4*       yo = (float4*)y;
        size_t tid = (size_t)blockIdx.x * 256 + threadIdx.x;
        const size_t stride = (size_t)1024 * 256;
        #pragma unroll
        for (int i = 0; i < 16; ++i) {
            yo[tid] = xi[tid];
            tid += stride;
        }
        return;
    }

    __shared__ float til[64][65];
    const int t   = threadIdx.x;
    const int r16 = t >> 4, c4 = t & 15;

    for (int p4 = 0; p4 < 4; ++p4) {
        const int tile = blockIdx.x + p4 * 1024;      // 0..4095
        const int n0 = (tile & 63) * 64;
        const int c0 = ((tile >> 6) & 3) * 64;
        const int b  = tile >> 8;

        const float*  xp  = x   + ((size_t)b * C_ + c0) * (size_t)N_ + n0;
        __bf16*       xbp = xbf + ((size_t)b * C_ + c0) * (size_t)N_ + n0;

        for (int p = 0; p < 4; ++p) {
            int row = r16 + p * 16;                   // c within tile
            float4 v = *(const float4*)(xp + (size_t)row * N_ + c4 * 4);
            til[row][c4 * 4 + 0] = v.x;
            til[row][c4 * 4 + 1] = v.y;
            til[row][c4 * 4 + 2] = v.z;
            til[row][c4 * 4 + 3] = v.w;
            bf16x4 w;
            w[0] = (__bf16)v.x; w[1] = (__bf16)v.y; w[2] = (__bf16)v.z; w[3] = (__bf16)v.w;
            *(bf16x4*)(xbp + (size_t)row * N_ + c4 * 4) = w;
        }
        __syncthreads();

        const int h  = n0 >> 9;
        const int d0 = n0 & 511;
        __bf16* xtp = xt + (((size_t)(b * NH_ + h) * D_ + d0) * C_) + c0;
        for (int p = 0; p < 4; ++p) {
            int dl = r16 + p * 16;                    // d within tile
            bf16x4 w;
            for (int j = 0; j < 4; ++j) w[j] = (__bf16)til[c4 * 4 + j][dl];
            *(bf16x4*)(xtp + (size_t)dl * C_ + c4 * 4) = w;
        }
        __syncthreads();
    }
}

// ---------------------------------------------------------------------------
// Kernel 1 (fused): energy = X X^T -> softmax -> P (LDS-resident, bf16)
//                   -> out = P @ X -> y = gamma*out + x.
// grid 512 (= BH_ * 4 row-tiles of 64 c-rows), block 256 (4 waves).
// XCD-chunked blockIdx swizzle: hw blocks round-robin across the 8 XCDs, so
// logical = (hw%8)*64 + hw/8 places logical blocks [4h..4h+3] (the 4 row-tiles
// of head h, which stream IDENTICAL xbf/xt data) on ONE XCD at ~the same time.
// The 3x redundant re-reads then hit that XCD's 4 MB L2 instead of HBM.
// LDS: 32 KB X/B union + 32 KB P + ~1.3 KB reductions -> 2 blocks/CU.
// ---------------------------------------------------------------------------
__global__ __launch_bounds__(256) void k_attn(const __bf16* __restrict__ xbf,
                                              const __bf16* __restrict__ xt,
                                              const float* __restrict__ x,
                                              const float* __restrict__ gamma,
                                              float* __restrict__ y) {
    const float g = *gamma;
    if (g == 0.0f) return;        // y already written by k_prep

    // XCD-chunked swizzle (bijective: 512 = 8 XCDs x 64)
    const int bid = ((blockIdx.x & 7) << 6) | (blockIdx.x >> 3);
    const int bh = bid >> 2;
    const int mt = bid & 3;
    const int b  = bh >> 3, h = bh & 7;
    const __bf16* xh = xbf + (size_t)b * C_ * N_ + (size_t)h * D_;  // row pitch N_
    const __bf16* bp = xt  + (size_t)bh * D_ * C_;                  // row pitch C_

    __shared__ __align__(16) __bf16 XBs[256][64];   // energy X-stage / PV B-stage (32 KB)
    __shared__ __align__(16) __bf16 Ps[4][64][64];  // P tiles per 64-k chunk (32 KB)
    __shared__ float  red[4][64];
    __shared__ float  rminf[64];
    __shared__ float  rsumf[64];

    const int t = threadIdx.x;
    const int wave = t >> 6, lane = t & 63;
    const int q = lane >> 4, l15 = lane & 15;
    const int skb = lane & 7;          // 16B block within a 64-wide row
    const int lr  = lane >> 3;         // row within an 8-row chunk

    // ---------------- energy phase: acc = X[mt rows] @ X^T (per-wave 64 cols)
    floatx4 acc[4][4] = {};

    for (int k0 = 0; k0 < D_; k0 += 64) {
        for (int p = 0; p < 8; ++p) {
            int chunk = wave * 8 + p;
            int row   = chunk * 8 + lr;
            const __bf16* src = xh + (size_t)row * N_ + k0 + ((skb ^ (row & 7)) << 3);
            gl_lds16(src, (char*)&XBs[0][0] + chunk * 1024);
        }
        __syncthreads();
        for (int kk = 0; kk < 2; ++kk) {
            bf16x8 af[4], bfv[4];
            for (int rt = 0; rt < 4; ++rt) {
                int row = mt * 64 + rt * 16 + l15;
                af[rt] = *(const bf16x8*)&XBs[row][sw(row, kk * 4 + q) * 8];
            }
            for (int ct = 0; ct < 4; ++ct) {
                int row = wave * 64 + ct * 16 + l15;
                bfv[ct] = *(const bf16x8*)&XBs[row][sw(row, kk * 4 + q) * 8];
            }
            for (int rt = 0; rt < 4; ++rt)
                for (int ct = 0; ct < 4; ++ct)
                    acc[rt][ct] = __builtin_amdgcn_mfma_f32_16x16x32_bf16(
                        af[rt], bfv[ct], acc[rt][ct], 0, 0, 0);
        }
        __syncthreads();
    }

    // ---------------- softmax: exp(rowmin - e) / rowsum (== softmax(max - e))
    float rm[4][4];
    for (int rt = 0; rt < 4; ++rt)
        for (int r = 0; r < 4; ++r) {
            float m = fminf(fminf(acc[rt][0][r], acc[rt][1][r]),
                            fminf(acc[rt][2][r], acc[rt][3][r]));
            m = fminf(m, __shfl_xor(m, 1));
            m = fminf(m, __shfl_xor(m, 2));
            m = fminf(m, __shfl_xor(m, 4));
            m = fminf(m, __shfl_xor(m, 8));
            rm[rt][r] = m;
        }
    if (l15 == 0)
        for (int rt = 0; rt < 4; ++rt)
            for (int r = 0; r < 4; ++r)
                red[wave][rt * 16 + q * 4 + r] = rm[rt][r];
    __syncthreads();
    if (t < 64)
        rminf[t] = fminf(fminf(red[0][t], red[1][t]), fminf(red[2][t], red[3][t]));
    __syncthreads();

    float sm[4][4];
    for (int rt = 0; rt < 4; ++rt)
        for (int r = 0; r < 4; ++r) {
            float rmv = rminf[rt * 16 + q * 4 + r];
            float s = 0.f;
            for (int ct = 0; ct < 4; ++ct) {
                float p = __expf(rmv - acc[rt][ct][r]);
                acc[rt][ct][r] = p;
                s += p;
            }
            s += __shfl_xor(s, 1);
            s += __shfl_xor(s, 2);
            s += __shfl_xor(s, 4);
            s += __shfl_xor(s, 8);
            sm[rt][r] = s;
        }
    if (l15 == 0)
        for (int rt = 0; rt < 4; ++rt)
            for (int r = 0; r < 4; ++r)
                red[wave][rt * 16 + q * 4 + r] = sm[rt][r];
    __syncthreads();
    if (t < 64)
        rsumf[t] = red[0][t] + red[1][t] + red[2][t] + red[3][t];
    __syncthreads();

    // ---------------- P -> LDS (bf16, XOR-swizzled like the As/Bs tiles).
    // Wave computed energy cols [wave*64, wave*64+64) == k-chunk 'wave' of P.
    for (int rt = 0; rt < 4; ++rt)
        for (int r = 0; r < 4; ++r) {
            int row = rt * 16 + q * 4 + r;
            float inv = 1.0f / rsumf[row];
            for (int ct = 0; ct < 4; ++ct) {
                int col = ct * 16 + l15;
                int cswz = (((col >> 3) ^ (row & 7)) << 3) | (col & 7);
                Ps[wave][row][cswz] = (__bf16)(acc[rt][ct][r] * inv);
            }
        }
    __syncthreads();

    // ---------------- PV phase: out[64 c][512 d] = P @ X, y = g*out + x.
    // Per d-half (256): wave owns a 64-d quarter; k-loop 4 x 64 staged from Xt.
    for (int dh = 0; dh < 2; ++dh) {
        floatx4 oacc[4][4] = {};
        for (int k0c = 0; k0c < 4; ++k0c) {
            for (int p = 0; p < 8; ++p) {
                int chunk = wave * 8 + p;            // 0..31
                int row   = chunk * 8 + lr;          // 0..255 = local d
                int dglob = dh * 256 + row;
                const __bf16* src = bp + (size_t)dglob * C_ + k0c * 64
                                       + ((skb ^ (row & 7)) << 3);
                gl_lds16(src, (char*)&XBs[0][0] + chunk * 1024);
            }
            __syncthreads();
            for (int kk = 0; kk < 2; ++kk) {
                bf16x8 af[4], bfv[4];
                for (int rt = 0; rt < 4; ++rt) {
                    int row = rt * 16 + l15;
                    af[rt] = *(const bf16x8*)&Ps[k0c][row][sw(row, kk * 4 + q) * 8];
                }
                for (int ct = 0; ct < 4; ++ct) {
                    int row = wave * 64 + ct * 16 + l15;   // local d
                    bfv[ct] = *(const bf16x8*)&XBs[row][sw(row, kk * 4 + q) * 8];
                }
                for (int rt = 0; rt < 4; ++rt)
                    for (int ct = 0; ct < 4; ++ct)
                        oacc[rt][ct] = __builtin_amdgcn_mfma_f32_16x16x32_bf16(
                            af[rt], bfv[ct], oacc[rt][ct], 0, 0, 0);
            }
            __syncthreads();
        }
        // epilogue for this d-half
        for (int rt = 0; rt < 4; ++rt)
            for (int r = 0; r < 4; ++r) {
                int c = mt * 64 + rt * 16 + q * 4 + r;
                size_t rowoff = ((size_t)b * C_ + c) * N_ + (size_t)h * D_
                              + dh * 256 + wave * 64;
                for (int ct = 0; ct < 4; ++ct) {
                    int d = ct * 16 + l15;
                    y[rowoff + d] = g * oacc[rt][ct][r] + x[rowoff + d];
                }
            }
    }
}

// ---------------------------------------------------------------------------
extern "C" void kernel_launch(void* const* d_in, const int* in_sizes, int n_in,
                              void* d_out, int out_size, void* d_ws, size_t ws_size,
                              hipStream_t stream) {
    const float* x     = (const float*)d_in[0];
    const float* gamma = (const float*)d_in[1];
    float*       y     = (float*)d_out;

    // ws layout: Xbf bf16 [b][c][n] (33.5 MB) | Xt bf16 [bh][d][c] (33.5 MB)
    __bf16* xbf  = (__bf16*)d_ws;
    __bf16* xt   = xbf + (size_t)B_ * C_ * N_;

    k_prep<<<1024, 256, 0, stream>>>(x, xbf, xt, gamma, y);
    k_attn<<<BH_ * 4, 256, 0, stream>>>(xbf, xt, x, gamma, y);
}

// Round 4
// 116.874 us; speedup vs baseline: 1.0150x; 1.0150x over previous
//
#include <hip/hip_runtime.h>

// Problem constants
#define B_   16
#define C_   256
#define N_   4096   // H*W
#define NH_  8
#define D_   512    // N_/NH_
#define BH_  128    // B_*NH_

typedef __bf16  bf16x8  __attribute__((ext_vector_type(8)));
typedef __bf16  bf16x4  __attribute__((ext_vector_type(4)));
typedef float   floatx4 __attribute__((ext_vector_type(4)));

// XOR swizzle of 8-element column blocks (XOR touches only the low 3 bits of
// the block index, so it permutes within each 8-block = 64-element group)
__device__ __forceinline__ int sw(int row, int kb) { return kb ^ (row & 7); }

// async global->LDS, 16B per lane. LDS dest is wave-uniform base + lane*16.
__device__ __forceinline__ void gl_lds16(const void* g, void* l) {
    __builtin_amdgcn_global_load_lds(
        (const __attribute__((address_space(1))) unsigned int*)g,
        (__attribute__((address_space(3))) unsigned int*)l, 16, 0, 0);
}

// ---------------------------------------------------------------------------
// gamma==0 fast path (algebraic zero-skip, exact): softmax rows sum to 1 ->
// out is finite -> gamma==0 => y == x bit-exactly. Copy runs in k_prep.
// ---------------------------------------------------------------------------

// ---------------------------------------------------------------------------
// Kernel 0: gamma!=0: x (fp32 [b][c][n]) -> Xbf (bf16) + Xt (bf16 [bh][d][c]).
//           gamma==0: y = x straight copy at HBM bandwidth.
// ---------------------------------------------------------------------------
__global__ __launch_bounds__(256) void k_prep(const float* __restrict__ x,
                                              __bf16* __restrict__ xbf,
                                              __bf16* __restrict__ xt,
                                              const float* __restrict__ gamma,
                                              float* __restrict__ y) {
    const float g = *gamma;
    if (g == 0.0f) {
        const float4* xi = (const float4*)x;
        float4*       yo = (float4*)y;
        size_t tid = (size_t)blockIdx.x * 256 + threadIdx.x;
        const size_t stride = (size_t)1024 * 256;
        #pragma unroll
        for (int i = 0; i < 16; ++i) {
            yo[tid] = xi[tid];
            tid += stride;
        }
        return;
    }

    __shared__ float til[64][65];
    const int t   = threadIdx.x;
    const int r16 = t >> 4, c4 = t & 15;

    for (int p4 = 0; p4 < 4; ++p4) {
        const int tile = blockIdx.x + p4 * 1024;      // 0..4095
        const int n0 = (tile & 63) * 64;
        const int c0 = ((tile >> 6) & 3) * 64;
        const int b  = tile >> 8;

        const float*  xp  = x   + ((size_t)b * C_ + c0) * (size_t)N_ + n0;
        __bf16*       xbp = xbf + ((size_t)b * C_ + c0) * (size_t)N_ + n0;

        for (int p = 0; p < 4; ++p) {
            int row = r16 + p * 16;                   // c within tile
            float4 v = *(const float4*)(xp + (size_t)row * N_ + c4 * 4);
            til[row][c4 * 4 + 0] = v.x;
            til[row][c4 * 4 + 1] = v.y;
            til[row][c4 * 4 + 2] = v.z;
            til[row][c4 * 4 + 3] = v.w;
            bf16x4 w;
            w[0] = (__bf16)v.x; w[1] = (__bf16)v.y; w[2] = (__bf16)v.z; w[3] = (__bf16)v.w;
            *(bf16x4*)(xbp + (size_t)row * N_ + c4 * 4) = w;
        }
        __syncthreads();

        const int h  = n0 >> 9;
        const int d0 = n0 & 511;
        __bf16* xtp = xt + (((size_t)(b * NH_ + h) * D_ + d0) * C_) + c0;
        for (int p = 0; p < 4; ++p) {
            int dl = r16 + p * 16;                    // d within tile
            bf16x4 w;
            for (int j = 0; j < 4; ++j) w[j] = (__bf16)til[c4 * 4 + j][dl];
            *(bf16x4*)(xtp + (size_t)dl * C_ + c4 * 4) = w;
        }
        __syncthreads();
    }
}

// ---------------------------------------------------------------------------
// Kernel 1 (fused, half-head blocks): grid 256 (= BH_ * 2 c-halves),
// block 512 (8 waves, wave grid wy x wx = 2 x 4).
//   energy: E[128c x 256k] = X[ch rows] @ X^T   (wave tile 64x64)
//   softmax(rowmin - E) -> P[128][256] bf16 in LDS (64 KB, XOR-swizzled)
//   PV: out[128c x 512d] = P @ Xt, y = gamma*out + x  (per d-half, tile 64x64)
// Redundancy: xbf + xt each read 2x per head (was 4x) -> k_attn 402->268 MB.
// LDS: 64 KB P + 32 KB stage + ~3 KB red = 99 KB -> 1 block/CU, 256 blocks.
// ---------------------------------------------------------------------------
__global__ __launch_bounds__(512) void k_attn(const __bf16* __restrict__ xbf,
                                              const __bf16* __restrict__ xt,
                                              const float* __restrict__ x,
                                              const float* __restrict__ gamma,
                                              float* __restrict__ y) {
    const float g = *gamma;
    if (g == 0.0f) return;        // y already written by k_prep

    // XCD-chunked swizzle (bijective: 256 = 8 XCDs x 32); pairs (2h,2h+1)
    // land on one XCD.
    const int bid = ((blockIdx.x & 7) << 5) | (blockIdx.x >> 3);
    const int bh = bid >> 1;          // head 0..127
    const int ch = bid & 1;           // c-half 0..1
    const int b  = bh >> 3, h = bh & 7;
    const __bf16* xh = xbf + (size_t)b * C_ * N_ + (size_t)h * D_;  // pitch N_
    const __bf16* bp = xt  + (size_t)bh * D_ * C_;                  // pitch C_

    __shared__ __align__(16) __bf16 Ps[128][256];   // P tile (64 KB)
    __shared__ __align__(16) __bf16 Stg[256][64];   // stage: energy X / PV Xt (32 KB)
    __shared__ float red[2][4][64];                 // per-(wy,wx) row partials
    __shared__ float rminf[128];
    __shared__ float rsumf[128];

    const int t = threadIdx.x;
    const int wave = t >> 6, lane = t & 63;
    const int q = lane >> 4, l15 = lane & 15;
    const int skb = lane & 7;          // 16B block within a 64-wide row
    const int lr  = lane >> 3;         // row within an 8-row chunk
    const int wy = wave >> 2, wx = wave & 3;

    // ---------------- energy phase: acc = X[ch*128 + wy*64 ..][.] @ X^T[wx*64 ..]
    floatx4 acc[4][4] = {};

    for (int k0 = 0; k0 < D_; k0 += 64) {
        for (int p = 0; p < 4; ++p) {
            int chunk = wave * 4 + p;          // 0..31
            int row   = chunk * 8 + lr;        // 0..255 (c)
            gl_lds16(xh + (size_t)row * N_ + k0 + ((skb ^ (row & 7)) << 3),
                     (char*)&Stg[0][0] + chunk * 1024);
        }
        __syncthreads();
        for (int kk = 0; kk < 2; ++kk) {
            bf16x8 af[4], bfv[4];
            for (int rt = 0; rt < 4; ++rt) {
                int row = ch * 128 + wy * 64 + rt * 16 + l15;
                af[rt] = *(const bf16x8*)&Stg[row][sw(row, kk * 4 + q) * 8];
            }
            for (int ct = 0; ct < 4; ++ct) {
                int row = wx * 64 + ct * 16 + l15;
                bfv[ct] = *(const bf16x8*)&Stg[row][sw(row, kk * 4 + q) * 8];
            }
            for (int rt = 0; rt < 4; ++rt)
                for (int ct = 0; ct < 4; ++ct)
                    acc[rt][ct] = __builtin_amdgcn_mfma_f32_16x16x32_bf16(
                        af[rt], bfv[ct], acc[rt][ct], 0, 0, 0);
        }
        __syncthreads();
    }

    // ---------------- softmax: exp(rowmin - e) / rowsum (== softmax(max - e))
    float rm[4][4];
    for (int rt = 0; rt < 4; ++rt)
        for (int r = 0; r < 4; ++r) {
            float m = fminf(fminf(acc[rt][0][r], acc[rt][1][r]),
                            fminf(acc[rt][2][r], acc[rt][3][r]));
            m = fminf(m, __shfl_xor(m, 1));
            m = fminf(m, __shfl_xor(m, 2));
            m = fminf(m, __shfl_xor(m, 4));
            m = fminf(m, __shfl_xor(m, 8));
            rm[rt][r] = m;
        }
    if (l15 == 0)
        for (int rt = 0; rt < 4; ++rt)
            for (int r = 0; r < 4; ++r)
                red[wy][wx][rt * 16 + q * 4 + r] = rm[rt][r];
    __syncthreads();
    if (t < 128)
        rminf[t] = fminf(fminf(red[t >> 6][0][t & 63], red[t >> 6][1][t & 63]),
                         fminf(red[t >> 6][2][t & 63], red[t >> 6][3][t & 63]));
    __syncthreads();

    float sm[4][4];
    for (int rt = 0; rt < 4; ++rt)
        for (int r = 0; r < 4; ++r) {
            float rmv = rminf[wy * 64 + rt * 16 + q * 4 + r];
            float s = 0.f;
            for (int ct = 0; ct < 4; ++ct) {
                float p = __expf(rmv - acc[rt][ct][r]);
                acc[rt][ct][r] = p;
                s += p;
            }
            s += __shfl_xor(s, 1);
            s += __shfl_xor(s, 2);
            s += __shfl_xor(s, 4);
            s += __shfl_xor(s, 8);
            sm[rt][r] = s;
        }
    if (l15 == 0)
        for (int rt = 0; rt < 4; ++rt)
            for (int r = 0; r < 4; ++r)
                red[wy][wx][rt * 16 + q * 4 + r] = sm[rt][r];
    __syncthreads();
    if (t < 128)
        rsumf[t] = red[t >> 6][0][t & 63] + red[t >> 6][1][t & 63]
                 + red[t >> 6][2][t & 63] + red[t >> 6][3][t & 63];
    __syncthreads();

    // ---------------- P -> LDS (bf16, XOR-swizzled col blocks)
    for (int rt = 0; rt < 4; ++rt)
        for (int r = 0; r < 4; ++r) {
            int row = wy * 64 + rt * 16 + q * 4 + r;   // local c 0..127
            float inv = 1.0f / rsumf[row];
            for (int ct = 0; ct < 4; ++ct) {
                int col = wx * 64 + ct * 16 + l15;     // k 0..255
                int cswz = (((col >> 3) ^ (row & 7)) << 3) | (col & 7);
                Ps[row][cswz] = (__bf16)(acc[rt][ct][r] * inv);
            }
        }
    __syncthreads();

    // ---------------- PV phase: out[128c][512d] = P @ Xt, per d-half of 256.
    for (int dh = 0; dh < 2; ++dh) {
        floatx4 oacc[4][4] = {};
        for (int k0c = 0; k0c < 4; ++k0c) {
            for (int p = 0; p < 4; ++p) {
                int chunk = wave * 4 + p;          // 0..31
                int row   = chunk * 8 + lr;        // local d 0..255
                int dglob = dh * 256 + row;
                gl_lds16(bp + (size_t)dglob * C_ + k0c * 64
                            + ((skb ^ (row & 7)) << 3),
                         (char*)&Stg[0][0] + chunk * 1024);
            }
            __syncthreads();
            for (int kk = 0; kk < 2; ++kk) {
                bf16x8 af[4], bfv[4];
                for (int rt = 0; rt < 4; ++rt) {
                    int row = wy * 64 + rt * 16 + l15;       // P row (local c)
                    af[rt] = *(const bf16x8*)&Ps[row][sw(row, k0c * 8 + kk * 4 + q) * 8];
                }
                for (int ct = 0; ct < 4; ++ct) {
                    int row = wx * 64 + ct * 16 + l15;       // local d
                    bfv[ct] = *(const bf16x8*)&Stg[row][sw(row, kk * 4 + q) * 8];
                }
                for (int rt = 0; rt < 4; ++rt)
                    for (int ct = 0; ct < 4; ++ct)
                        oacc[rt][ct] = __builtin_amdgcn_mfma_f32_16x16x32_bf16(
                            af[rt], bfv[ct], oacc[rt][ct], 0, 0, 0);
            }
            __syncthreads();
        }
        // epilogue for this d-half
        for (int rt = 0; rt < 4; ++rt)
            for (int r = 0; r < 4; ++r) {
                int c = ch * 128 + wy * 64 + rt * 16 + q * 4 + r;
                size_t rowoff = ((size_t)b * C_ + c) * N_ + (size_t)h * D_
                              + dh * 256 + wx * 64;
                for (int ct = 0; ct < 4; ++ct) {
                    int d = ct * 16 + l15;
                    y[rowoff + d] = g * oacc[rt][ct][r] + x[rowoff + d];
                }
            }
    }
}

// ---------------------------------------------------------------------------
extern "C" void kernel_launch(void* const* d_in, const int* in_sizes, int n_in,
                              void* d_out, int out_size, void* d_ws, size_t ws_size,
                              hipStream_t stream) {
    const float* x     = (const float*)d_in[0];
    const float* gamma = (const float*)d_in[1];
    float*       y     = (float*)d_out;

    // ws layout: Xbf bf16 [b][c][n] (33.5 MB) | Xt bf16 [bh][d][c] (33.5 MB)
    __bf16* xbf  = (__bf16*)d_ws;
    __bf16* xt   = xbf + (size_t)B_ * C_ * N_;

    k_prep<<<1024, 256, 0, stream>>>(x, xbf, xt, gamma, y);
    k_attn<<<BH_ * 2, 512, 0, stream>>>(xbf, xt, x, gamma, y);
}